// Round 4
// baseline (342.760 us; speedup 1.0000x reference)
//
#include <hip/hip_runtime.h>
#include <hip/hip_bf16.h>

// e3nn FullyConnectedTensorProduct (128x0e+128x1o)^2 -> 128x0e+128x1o, N=4096
// R4: R3 with the SLICE_EL units bug fixed (655360 elems = 128 chunks x 5120,
//     was 327680 which made the 16 weight slices overlap pairwise).
// ws layout: [WT bf16 20MB][X1g bf16 4MB][X2g bf16 4MB]

typedef __bf16 bf16;
typedef __bf16 bf16x8 __attribute__((ext_vector_type(8)));
typedef float f32x4 __attribute__((ext_vector_type(4)));
typedef float f32x2 __attribute__((ext_vector_type(2)));
typedef unsigned u32;

#define WT_BYTES  (5u*4u*128u*4096u*2u)     // 20971520 B = 16 slices x 655360 el x 2B
#define X1_BYTES  (16u*4u*32768u*2u)        // 4194304  ([tile16][usec4][u32][n256][q4] bf16)
#define SLICE_EL  655360u                    // elems per slice = 128 chunks x 5120
#define CHUNK_EL  5120u                      // elems per K-chunk (10 KB)

__device__ __forceinline__ float blo(u32 x){ return __uint_as_float(x << 16); }
__device__ __forceinline__ float bhi(u32 x){ return __uint_as_float(x & 0xffff0000u); }

__device__ __forceinline__ u32 cvtpk(float lo, float hi){
    u32 r;
    asm("v_cvt_pk_bf16_f32 %0, %1, %2" : "=v"(r) : "v"(lo), "v"(hi));
    return r;
}
__device__ __forceinline__ f32x2 pk_mul(f32x2 a, f32x2 b){
    f32x2 r; asm("v_pk_mul_f32 %0, %1, %2" : "=v"(r) : "v"(a), "v"(b)); return r;
}
__device__ __forceinline__ f32x2 pk_fma(f32x2 a, f32x2 b, f32x2 c){
    f32x2 r; asm("v_pk_fma_f32 %0, %1, %2, %3" : "=v"(r) : "v"(a), "v"(b), "v"(c)); return r;
}
__device__ __forceinline__ f32x2 pk_fma_n(f32x2 a, f32x2 b, f32x2 c){  // -a*b + c
    f32x2 r; asm("v_pk_fma_f32 %0, %1, %2, %3 neg_lo:[1,0,0] neg_hi:[1,0,0]"
                 : "=v"(r) : "v"(a), "v"(b), "v"(c)); return r;
}
__device__ __forceinline__ f32x2 sp(float s){ return (f32x2){s, s}; }

union Frag { u32 u[4]; bf16x8 v; };
__device__ __forceinline__ bf16x8 FR(const u32 a[4]){
    Frag f; f.u[0]=a[0]; f.u[1]=a[1]; f.u[2]=a[2]; f.u[3]=a[3]; return f.v;
}

__device__ __forceinline__ void gl_lds16(const bf16* g, bf16* l) {
    __builtin_amdgcn_global_load_lds(
        (const __attribute__((address_space(1))) void*)g,
        (__attribute__((address_space(3))) void*)l,
        16, 0, 0);
}

// ---- prologue: weights f32 [u][v][w] -> WT[slice][c][p][32w][4q-swz][8v] bf16 ----
__global__ __launch_bounds__(256) void pack_w_kernel(
    const float* __restrict__ w0, const float* __restrict__ w1,
    const float* __restrict__ w2, const float* __restrict__ w3,
    const float* __restrict__ w4, bf16* __restrict__ wt)
{
    __shared__ float tl[64][130];
    const int b = blockIdx.x;           // 640 = 5 paths x 128 u
    const int p = b >> 7;
    const int u = b & 127;
    const int usec = u >> 5;
    const int uin  = u & 31;
    const float* src = (p==0)?w0:(p==1)?w1:(p==2)?w2:(p==3)?w3:w4;
    const float scale = (p==0)?1.0f:(p==4)?0.40824829046386302f:0.57735026918962576f;

    for (int h = 0; h < 2; ++h) {       // two 64-v halves
        const float* spR = src + (size_t)u*16384 + (size_t)h*8192;
        #pragma unroll
        for (int k = 0; k < 8; ++k) {
            const int e4 = (k*256 + threadIdx.x) * 4;
            const float4 v4 = *(const float4*)(spR + e4);
            const int vi = e4 >> 7, w = e4 & 127;
            tl[vi][w+0]=v4.x; tl[vi][w+1]=v4.y; tl[vi][w+2]=v4.z; tl[vi][w+3]=v4.w;
        }
        __syncthreads();
        #pragma unroll
        for (int k = 0; k < 4; ++k) {
            const int cid = k*256 + threadIdx.x;     // 0..1023 16B-chunks
            const int vbh  = cid >> 9;
            const int wsec = (cid >> 7) & 3;
            const int w    = (cid >> 2) & 31;
            const int q    = cid & 3;
            const int vb   = h*2 + vbh;
            const int c    = vb*32 + uin;
            const int qs   = q ^ ((w >> 1) & 3);
            bf16x8 t8;
            #pragma unroll
            for (int j = 0; j < 8; ++j)
                t8[j] = (bf16)(tl[vbh*32 + q*8 + j][wsec*32 + w] * scale);
            *(bf16x8*)(wt + (size_t)(usec*4 + wsec)*SLICE_EL + (size_t)c*CHUNK_EL
                          + p*1024 + w*32 + qs*8) = t8;
        }
        __syncthreads();
    }
}

// ---- prologue: pack x1 -> [tile][usec][u32][n256][q4]; x2 -> [n][q][v] bf16 ----
__global__ __launch_bounds__(256) void pack_x_kernel(
    const float* __restrict__ x1s, const float* __restrict__ x1v,
    const float* __restrict__ x2s, const float* __restrict__ x2v,
    bf16* __restrict__ x1g, bf16* __restrict__ x2g)
{
    if (blockIdx.x < 128) {
        __shared__ uint2 tl[128][33];
        const int nb = blockIdx.x;
        #pragma unroll
        for (int k = 0; k < 16; ++k) {
            const int idx = k*256 + threadIdx.x;    // u fast
            const int u = idx & 127, nd = idx >> 7;
            const size_t i = (size_t)(nb*32 + nd)*128 + u;
            union { bf16 h[4]; uint2 u2; } tp;
            tp.h[0] = (bf16)x1s[i];
            tp.h[1] = (bf16)x1v[i*3 + 0];
            tp.h[2] = (bf16)x1v[i*3 + 1];
            tp.h[3] = (bf16)x1v[i*3 + 2];
            tl[u][nd] = tp.u2;
        }
        __syncthreads();
        uint2* og = (uint2*)x1g;
        const int t = nb >> 3, nd0 = (nb & 7) * 32;
        #pragma unroll
        for (int k = 0; k < 16; ++k) {
            const int idx = k*256 + threadIdx.x;    // nd fast
            const int u = idx >> 5, nd = idx & 31;
            og[(((t*4 + (u>>5))*32 + (u&31)) << 8) + nd0 + nd] = tl[u][nd];
        }
    } else {
        const int tt = (blockIdx.x - 128)*256 + threadIdx.x;
        const int n = tt >> 7, v = tt & 127;
        const size_t b = (size_t)n*512;
        const size_t i = (size_t)n*128 + v;
        x2g[b +   0 + v] = (bf16)x2s[i];
        x2g[b + 128 + v] = (bf16)x2v[i*3 + 0];
        x2g[b + 256 + v] = (bf16)x2v[i*3 + 1];
        x2g[b + 384 + v] = (bf16)x2v[i*3 + 2];
    }
}

// ---- main: 256 WGs = 16 node-tiles(256) x 4 u-sec x 4 w-sec, 512 thr ----
__global__ __launch_bounds__(512, 2) void tp_main(
    const bf16* __restrict__ wt, const bf16* __restrict__ x1g,
    const bf16* __restrict__ x2g, float* __restrict__ out)
{
    __shared__ __align__(16) bf16 wlds[2*CHUNK_EL];  // 20 KB dbuf weights
    __shared__ __align__(16) bf16 x1lds[32768];      // 64 KB x1 slice [u32][n256][q4]

    const int tid  = threadIdx.x;
    const int lane = tid & 63;
    const int wv   = tid >> 6;
    const int kg   = lane >> 4;
    const int lr   = lane & 15;

    const int b    = blockIdx.x;
    const int s    = (b & 7)*2 + ((b >> 3) & 1);  // weight slice 0..15 (XCD-pinned)
    const int t    = b >> 4;                      // node tile 0..15
    const int usec = s >> 2;
    const int wsec = s & 3;

    const bf16* wstream = wt + (size_t)s * SLICE_EL;

    int boff[2];
    #pragma unroll
    for (int ct = 0; ct < 2; ++ct) {
        const int wp = ct*16 + lr;
        boff[ct] = wp*32 + ((kg ^ ((wp >> 1) & 3)) * 8);
    }

    // stage x1 slice (64KB) + weight chunk 0
    {
        const bf16* src = x1g + ((size_t)(t*4 + usec) << 15);
        #pragma unroll
        for (int r = 0; r < 8; ++r)
            gl_lds16(src + (wv*8 + r)*512 + lane*8, x1lds + (wv*8 + r)*512);
    }
    {
        gl_lds16(wstream + tid*8, wlds + wv*512);
        if (wv < 2) gl_lds16(wstream + 4096 + tid*8, wlds + 4096 + wv*512);
    }
    __syncthreads();

    f32x4 acc[2][2][4];
    #pragma unroll
    for (int a = 0; a < 2; ++a)
        #pragma unroll
        for (int c2 = 0; c2 < 2; ++c2)
            #pragma unroll
            for (int d = 0; d < 4; ++d)
                acc[a][c2][d] = (f32x4){0.f, 0.f, 0.f, 0.f};

    f32x2 xp[2][4][4];   // [rt][q][vpair]
    const bf16* wnext = wstream + CHUNK_EL;

    auto body = [&](int urel, int nb) {
        // stage next chunk (linear LDS dst, pointer-increment src)
        gl_lds16(wnext + tid*8, wlds + (nb^1)*CHUNK_EL + wv*512);
        if (wv < 2) gl_lds16(wnext + 4096 + tid*8, wlds + (nb^1)*CHUNK_EL + 4096 + wv*512);
        wnext += CHUNK_EL;

        // B fragments (5 paths x 2 col-tiles)
        bf16x8 bfr[5][2];
        const bf16* wb = wlds + nb*CHUNK_EL;
        #pragma unroll
        for (int p = 0; p < 5; ++p)
            #pragma unroll
            for (int ct = 0; ct < 2; ++ct)
                bfr[p][ct] = *(const bf16x8*)(wb + p*1024 + boff[ct]);

        #pragma unroll
        for (int rt = 0; rt < 2; ++rt) {
            const int nodel = wv*32 + rt*16 + lr;
            const uint2 h1 = *(const uint2*)(x1lds + urel*1024 + nodel*4);
            const f32x2 ps1 = sp(blo(h1.x));
            f32x2 pv[3];
            pv[0] = sp(bhi(h1.x)); pv[1] = sp(blo(h1.y)); pv[2] = sp(bhi(h1.y));

            // ---- scalar-output channels: sss, vvs ----
            {
                u32 f0[4], f1[4];
                #pragma unroll
                for (int j = 0; j < 4; ++j) {
                    const f32x2 s2 = xp[rt][0][j];
                    f32x2 cs = pk_mul(ps1, s2);
                    f32x2 cd = pk_mul(pv[0], xp[rt][1][j]);
                    cd = pk_fma(pv[1], xp[rt][2][j], cd);
                    cd = pk_fma(pv[2], xp[rt][3][j], cd);
                    f0[j] = cvtpk(cs.x, cs.y);
                    f1[j] = cvtpk(cd.x, cd.y);
                }
                #pragma unroll
                for (int ct = 0; ct < 2; ++ct) {
                    acc[rt][ct][0] = __builtin_amdgcn_mfma_f32_16x16x32_bf16(FR(f0), bfr[0][ct], acc[rt][ct][0], 0,0,0);
                    acc[rt][ct][0] = __builtin_amdgcn_mfma_f32_16x16x32_bf16(FR(f1), bfr[1][ct], acc[rt][ct][0], 0,0,0);
                }
            }
            // ---- vector-output channels per component k: svv, vsv, vvv(cross) ----
            #pragma unroll
            for (int k = 0; k < 3; ++k) {
                const int k1 = (k+1) % 3, k2 = (k+2) % 3;
                u32 fa[4], fb[4], fc[4];
                #pragma unroll
                for (int j = 0; j < 4; ++j) {
                    const f32x2 s2  = xp[rt][0][j];
                    const f32x2 vk  = xp[rt][1+k][j];
                    const f32x2 vk1 = xp[rt][1+k1][j];
                    const f32x2 vk2 = xp[rt][1+k2][j];
                    f32x2 c_sv = pk_mul(ps1, vk);
                    f32x2 c_vs = pk_mul(pv[k], s2);
                    f32x2 tx   = pk_mul(pv[k1], vk2);
                    f32x2 c_x  = pk_fma_n(pv[k2], vk1, tx);
                    fa[j] = cvtpk(c_sv.x, c_sv.y);
                    fb[j] = cvtpk(c_vs.x, c_vs.y);
                    fc[j] = cvtpk(c_x.x,  c_x.y);
                }
                #pragma unroll
                for (int ct = 0; ct < 2; ++ct) {
                    acc[rt][ct][1+k] = __builtin_amdgcn_mfma_f32_16x16x32_bf16(FR(fa), bfr[2][ct], acc[rt][ct][1+k], 0,0,0);
                    acc[rt][ct][1+k] = __builtin_amdgcn_mfma_f32_16x16x32_bf16(FR(fb), bfr[3][ct], acc[rt][ct][1+k], 0,0,0);
                    acc[rt][ct][1+k] = __builtin_amdgcn_mfma_f32_16x16x32_bf16(FR(fc), bfr[4][ct], acc[rt][ct][1+k], 0,0,0);
                }
            }
        }
        __syncthreads();
    };

    for (int vb = 0; vb < 4; ++vb) {
        // refresh x2 register slices for this v-block (issued before staging)
        #pragma unroll
        for (int rt = 0; rt < 2; ++rt) {
            const int n = t*256 + wv*32 + rt*16 + lr;
            #pragma unroll
            for (int q = 0; q < 4; ++q) {
                const uint4 h = *(const uint4*)(x2g + ((size_t)(n*4 + q) << 7) + vb*32 + kg*8);
                xp[rt][q][0] = (f32x2){blo(h.x), bhi(h.x)};
                xp[rt][q][1] = (f32x2){blo(h.y), bhi(h.y)};
                xp[rt][q][2] = (f32x2){blo(h.z), bhi(h.z)};
                xp[rt][q][3] = (f32x2){blo(h.w), bhi(h.w)};
            }
        }
        for (int u2 = 0; u2 < 16; ++u2) {
            body(u2*2 + 0, 0);
            body(u2*2 + 1, 1);
        }
    }

    // epilogue: accumulate u-section partials into d_out
    #pragma unroll
    for (int rt = 0; rt < 2; ++rt) {
        #pragma unroll
        for (int ct = 0; ct < 2; ++ct) {
            const int w = wsec*32 + ct*16 + lr;
            #pragma unroll
            for (int j = 0; j < 4; ++j) {
                const int n = t*256 + wv*32 + rt*16 + kg*4 + j;
                float* op = out + (size_t)n*512;
                unsafeAtomicAdd(op + w,             acc[rt][ct][0][j]);
                unsafeAtomicAdd(op + 128 + w*3 + 0, acc[rt][ct][1][j]);
                unsafeAtomicAdd(op + 128 + w*3 + 1, acc[rt][ct][2][j]);
                unsafeAtomicAdd(op + 128 + w*3 + 2, acc[rt][ct][3][j]);
            }
        }
    }
}

extern "C" void kernel_launch(void* const* d_in, const int* in_sizes, int n_in,
                              void* d_out, int out_size, void* d_ws, size_t ws_size,
                              hipStream_t stream)
{
    const float* x1s = (const float*)d_in[0];
    const float* x1v = (const float*)d_in[1];
    const float* x2s = (const float*)d_in[2];
    const float* x2v = (const float*)d_in[3];
    const float* w0  = (const float*)d_in[4];
    const float* w1  = (const float*)d_in[5];
    const float* w2  = (const float*)d_in[6];
    const float* w3  = (const float*)d_in[7];
    const float* w4  = (const float*)d_in[8];

    bf16* wtb = (bf16*)d_ws;
    bf16* x1g = (bf16*)((char*)d_ws + WT_BYTES);
    bf16* x2g = (bf16*)((char*)d_ws + WT_BYTES + X1_BYTES);
    float* out = (float*)d_out;

    pack_w_kernel<<<640, 256, 0, stream>>>(w0, w1, w2, w3, w4, wtb);
    pack_x_kernel<<<2176, 256, 0, stream>>>(x1s, x1v, x2s, x2v, x1g, x2g);
    hipMemsetAsync(d_out, 0, (size_t)out_size*sizeof(float), stream);
    tp_main<<<256, 512, 0, stream>>>(wtb, x1g, x2g, out);
}

// Round 5
// 318.440 us; speedup vs baseline: 1.0764x; 1.0764x over previous
//
#include <hip/hip_runtime.h>
#include <hip/hip_bf16.h>

// e3nn FullyConnectedTensorProduct (128x0e+128x1o)^2 -> 128x0e+128x1o, N=4096
// R5: occupancy fix — node-tile 128 (x1lds 32KB, LDS 52KB -> 2 WG/CU,
//     16 waves/CU), grid 512 = 32 tiles x 16 XCD-pinned slices.
// ws layout: [WT bf16 20MB][X1g bf16 4MB][X2g bf16 4MB]

typedef __bf16 bf16;
typedef __bf16 bf16x8 __attribute__((ext_vector_type(8)));
typedef float f32x4 __attribute__((ext_vector_type(4)));
typedef float f32x2 __attribute__((ext_vector_type(2)));
typedef unsigned u32;

#define WT_BYTES  (5u*4u*128u*4096u*2u)     // 20971520 B = 16 slices x 655360 el x 2B
#define X1_BYTES  (32u*4u*16384u*2u)        // 4194304  ([tile32][usec4][u32][n128][q4] bf16)
#define SLICE_EL  655360u                    // elems per slice = 128 chunks x 5120
#define CHUNK_EL  5120u                      // elems per K-chunk (10 KB)

__device__ __forceinline__ float blo(u32 x){ return __uint_as_float(x << 16); }
__device__ __forceinline__ float bhi(u32 x){ return __uint_as_float(x & 0xffff0000u); }

__device__ __forceinline__ u32 cvtpk(float lo, float hi){
    u32 r;
    asm("v_cvt_pk_bf16_f32 %0, %1, %2" : "=v"(r) : "v"(lo), "v"(hi));
    return r;
}
__device__ __forceinline__ f32x2 pk_mul(f32x2 a, f32x2 b){
    f32x2 r; asm("v_pk_mul_f32 %0, %1, %2" : "=v"(r) : "v"(a), "v"(b)); return r;
}
__device__ __forceinline__ f32x2 pk_fma(f32x2 a, f32x2 b, f32x2 c){
    f32x2 r; asm("v_pk_fma_f32 %0, %1, %2, %3" : "=v"(r) : "v"(a), "v"(b), "v"(c)); return r;
}
__device__ __forceinline__ f32x2 pk_fma_n(f32x2 a, f32x2 b, f32x2 c){  // -a*b + c
    f32x2 r; asm("v_pk_fma_f32 %0, %1, %2, %3 neg_lo:[1,0,0] neg_hi:[1,0,0]"
                 : "=v"(r) : "v"(a), "v"(b), "v"(c)); return r;
}
__device__ __forceinline__ f32x2 sp(float s){ return (f32x2){s, s}; }

union Frag { u32 u[4]; bf16x8 v; };
__device__ __forceinline__ bf16x8 FR(const u32 a[4]){
    Frag f; f.u[0]=a[0]; f.u[1]=a[1]; f.u[2]=a[2]; f.u[3]=a[3]; return f.v;
}

__device__ __forceinline__ void gl_lds16(const bf16* g, bf16* l) {
    __builtin_amdgcn_global_load_lds(
        (const __attribute__((address_space(1))) void*)g,
        (__attribute__((address_space(3))) void*)l,
        16, 0, 0);
}

// ---- prologue: weights f32 [u][v][w] -> WT[slice][c][p][32w][4q-swz][8v] bf16 ----
__global__ __launch_bounds__(256) void pack_w_kernel(
    const float* __restrict__ w0, const float* __restrict__ w1,
    const float* __restrict__ w2, const float* __restrict__ w3,
    const float* __restrict__ w4, bf16* __restrict__ wt)
{
    __shared__ float tl[64][130];
    const int b = blockIdx.x;           // 640 = 5 paths x 128 u
    const int p = b >> 7;
    const int u = b & 127;
    const int usec = u >> 5;
    const int uin  = u & 31;
    const float* src = (p==0)?w0:(p==1)?w1:(p==2)?w2:(p==3)?w3:w4;
    const float scale = (p==0)?1.0f:(p==4)?0.40824829046386302f:0.57735026918962576f;

    for (int h = 0; h < 2; ++h) {       // two 64-v halves
        const float* spR = src + (size_t)u*16384 + (size_t)h*8192;
        #pragma unroll
        for (int k = 0; k < 8; ++k) {
            const int e4 = (k*256 + threadIdx.x) * 4;
            const float4 v4 = *(const float4*)(spR + e4);
            const int vi = e4 >> 7, w = e4 & 127;
            tl[vi][w+0]=v4.x; tl[vi][w+1]=v4.y; tl[vi][w+2]=v4.z; tl[vi][w+3]=v4.w;
        }
        __syncthreads();
        #pragma unroll
        for (int k = 0; k < 4; ++k) {
            const int cid = k*256 + threadIdx.x;     // 0..1023 16B-chunks
            const int vbh  = cid >> 9;
            const int wsec = (cid >> 7) & 3;
            const int w    = (cid >> 2) & 31;
            const int q    = cid & 3;
            const int vb   = h*2 + vbh;
            const int c    = vb*32 + uin;
            const int qs   = q ^ ((w >> 1) & 3);
            bf16x8 t8;
            #pragma unroll
            for (int j = 0; j < 8; ++j)
                t8[j] = (bf16)(tl[vbh*32 + q*8 + j][wsec*32 + w] * scale);
            *(bf16x8*)(wt + (size_t)(usec*4 + wsec)*SLICE_EL + (size_t)c*CHUNK_EL
                          + p*1024 + w*32 + qs*8) = t8;
        }
        __syncthreads();
    }
}

// ---- prologue: pack x1 -> [tile32][usec][u32][n128][q4]; x2 -> [n][q][v] bf16 ----
__global__ __launch_bounds__(256) void pack_x_kernel(
    const float* __restrict__ x1s, const float* __restrict__ x1v,
    const float* __restrict__ x2s, const float* __restrict__ x2v,
    bf16* __restrict__ x1g, bf16* __restrict__ x2g)
{
    if (blockIdx.x < 128) {
        __shared__ uint2 tl[128][33];
        const int nb = blockIdx.x;      // 32-node block
        #pragma unroll
        for (int k = 0; k < 16; ++k) {
            const int idx = k*256 + threadIdx.x;    // u fast
            const int u = idx & 127, nd = idx >> 7;
            const size_t i = (size_t)(nb*32 + nd)*128 + u;
            union { bf16 h[4]; uint2 u2; } tp;
            tp.h[0] = (bf16)x1s[i];
            tp.h[1] = (bf16)x1v[i*3 + 0];
            tp.h[2] = (bf16)x1v[i*3 + 1];
            tp.h[3] = (bf16)x1v[i*3 + 2];
            tl[u][nd] = tp.u2;
        }
        __syncthreads();
        uint2* og = (uint2*)x1g;
        const int t = nb >> 2, nd0 = (nb & 3) * 32;   // tile of 128 nodes
        #pragma unroll
        for (int k = 0; k < 16; ++k) {
            const int idx = k*256 + threadIdx.x;    // nd fast
            const int u = idx >> 5, nd = idx & 31;
            og[(((t*4 + (u>>5))*32 + (u&31)) << 7) + nd0 + nd] = tl[u][nd];
        }
    } else {
        const int tt = (blockIdx.x - 128)*256 + threadIdx.x;
        const int n = tt >> 7, v = tt & 127;
        const size_t b = (size_t)n*512;
        const size_t i = (size_t)n*128 + v;
        x2g[b +   0 + v] = (bf16)x2s[i];
        x2g[b + 128 + v] = (bf16)x2v[i*3 + 0];
        x2g[b + 256 + v] = (bf16)x2v[i*3 + 1];
        x2g[b + 384 + v] = (bf16)x2v[i*3 + 2];
    }
}

// ---- main: 512 WGs = 32 node-tiles(128) x 4 u-sec x 4 w-sec, 512 thr ----
// XCD-pinned slices: b&7 = XCD hosts slices {2x,2x+1} (2.5MB, L2-resident).
// wave = 16 nodes x 32 w (1 rt x 2 ct MFMA tiles). 2 WG/CU, 16 waves/CU.
__global__ __launch_bounds__(512, 4) void tp_main(
    const bf16* __restrict__ wt, const bf16* __restrict__ x1g,
    const bf16* __restrict__ x2g, float* __restrict__ out)
{
    __shared__ __align__(16) bf16 wlds[2*CHUNK_EL];  // 20 KB dbuf weights
    __shared__ __align__(16) bf16 x1lds[16384];      // 32 KB x1 slice [u32][n128][q4]

    const int tid  = threadIdx.x;
    const int lane = tid & 63;
    const int wv   = tid >> 6;
    const int kg   = lane >> 4;
    const int lr   = lane & 15;

    const int b    = blockIdx.x;
    const int s    = (b & 7)*2 + ((b >> 3) & 1);  // weight slice 0..15 (XCD-pinned)
    const int t    = b >> 4;                      // node tile 0..31
    const int usec = s >> 2;
    const int wsec = s & 3;

    const bf16* wstream = wt + (size_t)s * SLICE_EL;

    int boff[2];
    #pragma unroll
    for (int ct = 0; ct < 2; ++ct) {
        const int wp = ct*16 + lr;
        boff[ct] = wp*32 + ((kg ^ ((wp >> 1) & 3)) * 8);
    }

    // stage x1 slice (32KB) + weight chunk 0
    {
        const bf16* src = x1g + ((size_t)(t*4 + usec) << 14);
        #pragma unroll
        for (int r = 0; r < 4; ++r)
            gl_lds16(src + (wv*4 + r)*512 + lane*8, x1lds + (wv*4 + r)*512);
    }
    {
        gl_lds16(wstream + tid*8, wlds + wv*512);
        if (wv < 2) gl_lds16(wstream + 4096 + tid*8, wlds + 4096 + wv*512);
    }
    __syncthreads();

    f32x4 acc[2][4];
    #pragma unroll
    for (int c2 = 0; c2 < 2; ++c2)
        #pragma unroll
        for (int d = 0; d < 4; ++d)
            acc[c2][d] = (f32x4){0.f, 0.f, 0.f, 0.f};

    f32x2 xp[4][4];   // [q][vpair]
    const bf16* wnext = wstream + CHUNK_EL;

    auto body = [&](int urel, int nb) {
        // stage next chunk (linear LDS dst, pointer-increment src)
        gl_lds16(wnext + tid*8, wlds + (nb^1)*CHUNK_EL + wv*512);
        if (wv < 2) gl_lds16(wnext + 4096 + tid*8, wlds + (nb^1)*CHUNK_EL + 4096 + wv*512);
        wnext += CHUNK_EL;

        // B fragments (5 paths x 2 col-tiles)
        bf16x8 bfr[5][2];
        const bf16* wb = wlds + nb*CHUNK_EL;
        #pragma unroll
        for (int p = 0; p < 5; ++p)
            #pragma unroll
            for (int ct = 0; ct < 2; ++ct)
                bfr[p][ct] = *(const bf16x8*)(wb + p*1024 + boff[ct]);

        {
            const int nodel = wv*16 + lr;
            const uint2 h1 = *(const uint2*)(x1lds + urel*512 + nodel*4);
            const f32x2 ps1 = sp(blo(h1.x));
            f32x2 pv[3];
            pv[0] = sp(bhi(h1.x)); pv[1] = sp(blo(h1.y)); pv[2] = sp(bhi(h1.y));

            // ---- scalar-output channels: sss, vvs ----
            {
                u32 f0[4], f1[4];
                #pragma unroll
                for (int j = 0; j < 4; ++j) {
                    const f32x2 s2 = xp[0][j];
                    f32x2 cs = pk_mul(ps1, s2);
                    f32x2 cd = pk_mul(pv[0], xp[1][j]);
                    cd = pk_fma(pv[1], xp[2][j], cd);
                    cd = pk_fma(pv[2], xp[3][j], cd);
                    f0[j] = cvtpk(cs.x, cs.y);
                    f1[j] = cvtpk(cd.x, cd.y);
                }
                #pragma unroll
                for (int ct = 0; ct < 2; ++ct) {
                    acc[ct][0] = __builtin_amdgcn_mfma_f32_16x16x32_bf16(FR(f0), bfr[0][ct], acc[ct][0], 0,0,0);
                    acc[ct][0] = __builtin_amdgcn_mfma_f32_16x16x32_bf16(FR(f1), bfr[1][ct], acc[ct][0], 0,0,0);
                }
            }
            // ---- vector-output channels per component k: svv, vsv, vvv(cross) ----
            #pragma unroll
            for (int k = 0; k < 3; ++k) {
                const int k1 = (k+1) % 3, k2 = (k+2) % 3;
                u32 fa[4], fb[4], fc[4];
                #pragma unroll
                for (int j = 0; j < 4; ++j) {
                    const f32x2 s2  = xp[0][j];
                    const f32x2 vk  = xp[1+k][j];
                    const f32x2 vk1 = xp[1+k1][j];
                    const f32x2 vk2 = xp[1+k2][j];
                    f32x2 c_sv = pk_mul(ps1, vk);
                    f32x2 c_vs = pk_mul(pv[k], s2);
                    f32x2 tx   = pk_mul(pv[k1], vk2);
                    f32x2 c_x  = pk_fma_n(pv[k2], vk1, tx);
                    fa[j] = cvtpk(c_sv.x, c_sv.y);
                    fb[j] = cvtpk(c_vs.x, c_vs.y);
                    fc[j] = cvtpk(c_x.x,  c_x.y);
                }
                #pragma unroll
                for (int ct = 0; ct < 2; ++ct) {
                    acc[ct][1+k] = __builtin_amdgcn_mfma_f32_16x16x32_bf16(FR(fa), bfr[2][ct], acc[ct][1+k], 0,0,0);
                    acc[ct][1+k] = __builtin_amdgcn_mfma_f32_16x16x32_bf16(FR(fb), bfr[3][ct], acc[ct][1+k], 0,0,0);
                    acc[ct][1+k] = __builtin_amdgcn_mfma_f32_16x16x32_bf16(FR(fc), bfr[4][ct], acc[ct][1+k], 0,0,0);
                }
            }
        }
        __syncthreads();
    };

    for (int vb = 0; vb < 4; ++vb) {
        // refresh x2 register slice for this v-block (issued before staging)
        {
            const int n = t*128 + wv*16 + lr;
            #pragma unroll
            for (int q = 0; q < 4; ++q) {
                const uint4 h = *(const uint4*)(x2g + ((size_t)(n*4 + q) << 7) + vb*32 + kg*8);
                xp[q][0] = (f32x2){blo(h.x), bhi(h.x)};
                xp[q][1] = (f32x2){blo(h.y), bhi(h.y)};
                xp[q][2] = (f32x2){blo(h.z), bhi(h.z)};
                xp[q][3] = (f32x2){blo(h.w), bhi(h.w)};
            }
        }
        for (int u2 = 0; u2 < 16; ++u2) {
            body(u2*2 + 0, 0);
            body(u2*2 + 1, 1);
        }
    }

    // epilogue: accumulate u-section partials into d_out
    #pragma unroll
    for (int ct = 0; ct < 2; ++ct) {
        const int w = wsec*32 + ct*16 + lr;
        #pragma unroll
        for (int j = 0; j < 4; ++j) {
            const int n = t*128 + wv*16 + kg*4 + j;
            float* op = out + (size_t)n*512;
            unsafeAtomicAdd(op + w,             acc[ct][0][j]);
            unsafeAtomicAdd(op + 128 + w*3 + 0, acc[ct][1][j]);
            unsafeAtomicAdd(op + 128 + w*3 + 1, acc[ct][2][j]);
            unsafeAtomicAdd(op + 128 + w*3 + 2, acc[ct][3][j]);
        }
    }
}

extern "C" void kernel_launch(void* const* d_in, const int* in_sizes, int n_in,
                              void* d_out, int out_size, void* d_ws, size_t ws_size,
                              hipStream_t stream)
{
    const float* x1s = (const float*)d_in[0];
    const float* x1v = (const float*)d_in[1];
    const float* x2s = (const float*)d_in[2];
    const float* x2v = (const float*)d_in[3];
    const float* w0  = (const float*)d_in[4];
    const float* w1  = (const float*)d_in[5];
    const float* w2  = (const float*)d_in[6];
    const float* w3  = (const float*)d_in[7];
    const float* w4  = (const float*)d_in[8];

    bf16* wtb = (bf16*)d_ws;
    bf16* x1g = (bf16*)((char*)d_ws + WT_BYTES);
    bf16* x2g = (bf16*)((char*)d_ws + WT_BYTES + X1_BYTES);
    float* out = (float*)d_out;

    pack_w_kernel<<<640, 256, 0, stream>>>(w0, w1, w2, w3, w4, wtb);
    pack_x_kernel<<<2176, 256, 0, stream>>>(x1s, x1v, x2s, x2v, x1g, x2g);
    hipMemsetAsync(d_out, 0, (size_t)out_size*sizeof(float), stream);
    tp_main<<<512, 512, 0, stream>>>(wtb, x1g, x2g, out);
}

// Round 6
// 313.208 us; speedup vs baseline: 1.0944x; 1.0167x over previous
//
#include <hip/hip_runtime.h>
#include <hip/hip_bf16.h>

// e3nn FullyConnectedTensorProduct (128x0e+128x1o)^2 -> 128x0e+128x1o, N=4096
// R6: R5 + pipelined weight staging: 4 LDS buffers, stage c+2 during body c,
//     counted s_waitcnt vmcnt(4) + raw s_barrier (no vmcnt(0) drain in loop).
// ws layout: [WT bf16 20MB][X1g bf16 4MB][X2g bf16 4MB]

typedef __bf16 bf16;
typedef __bf16 bf16x8 __attribute__((ext_vector_type(8)));
typedef float f32x4 __attribute__((ext_vector_type(4)));
typedef float f32x2 __attribute__((ext_vector_type(2)));
typedef unsigned u32;

#define WT_BYTES  (5u*4u*128u*4096u*2u)     // 20971520 B = 16 slices x 655360 el x 2B
#define X1_BYTES  (32u*4u*16384u*2u)        // 4194304  ([tile32][usec4][u32][n128][q4] bf16)
#define SLICE_EL  655360u                    // elems per slice = 128 chunks x 5120
#define CHUNK_EL  5120u                      // elems per K-chunk (10 KB)

__device__ __forceinline__ float blo(u32 x){ return __uint_as_float(x << 16); }
__device__ __forceinline__ float bhi(u32 x){ return __uint_as_float(x & 0xffff0000u); }

__device__ __forceinline__ u32 cvtpk(float lo, float hi){
    u32 r;
    asm("v_cvt_pk_bf16_f32 %0, %1, %2" : "=v"(r) : "v"(lo), "v"(hi));
    return r;
}
__device__ __forceinline__ f32x2 pk_mul(f32x2 a, f32x2 b){
    f32x2 r; asm("v_pk_mul_f32 %0, %1, %2" : "=v"(r) : "v"(a), "v"(b)); return r;
}
__device__ __forceinline__ f32x2 pk_fma(f32x2 a, f32x2 b, f32x2 c){
    f32x2 r; asm("v_pk_fma_f32 %0, %1, %2, %3" : "=v"(r) : "v"(a), "v"(b), "v"(c)); return r;
}
__device__ __forceinline__ f32x2 pk_fma_n(f32x2 a, f32x2 b, f32x2 c){  // -a*b + c
    f32x2 r; asm("v_pk_fma_f32 %0, %1, %2, %3 neg_lo:[1,0,0] neg_hi:[1,0,0]"
                 : "=v"(r) : "v"(a), "v"(b), "v"(c)); return r;
}
__device__ __forceinline__ f32x2 sp(float s){ return (f32x2){s, s}; }

union Frag { u32 u[4]; bf16x8 v; };
__device__ __forceinline__ bf16x8 FR(const u32 a[4]){
    Frag f; f.u[0]=a[0]; f.u[1]=a[1]; f.u[2]=a[2]; f.u[3]=a[3]; return f.v;
}

__device__ __forceinline__ void gl_lds16(const bf16* g, bf16* l) {
    __builtin_amdgcn_global_load_lds(
        (const __attribute__((address_space(1))) void*)g,
        (__attribute__((address_space(3))) void*)l,
        16, 0, 0);
}

// ---- prologue: weights f32 [u][v][w] -> WT[slice][c][p][32w][4q-swz][8v] bf16 ----
__global__ __launch_bounds__(256) void pack_w_kernel(
    const float* __restrict__ w0, const float* __restrict__ w1,
    const float* __restrict__ w2, const float* __restrict__ w3,
    const float* __restrict__ w4, bf16* __restrict__ wt)
{
    __shared__ float tl[64][130];
    const int b = blockIdx.x;           // 640 = 5 paths x 128 u
    const int p = b >> 7;
    const int u = b & 127;
    const int usec = u >> 5;
    const int uin  = u & 31;
    const float* src = (p==0)?w0:(p==1)?w1:(p==2)?w2:(p==3)?w3:w4;
    const float scale = (p==0)?1.0f:(p==4)?0.40824829046386302f:0.57735026918962576f;

    for (int h = 0; h < 2; ++h) {       // two 64-v halves
        const float* spR = src + (size_t)u*16384 + (size_t)h*8192;
        #pragma unroll
        for (int k = 0; k < 8; ++k) {
            const int e4 = (k*256 + threadIdx.x) * 4;
            const float4 v4 = *(const float4*)(spR + e4);
            const int vi = e4 >> 7, w = e4 & 127;
            tl[vi][w+0]=v4.x; tl[vi][w+1]=v4.y; tl[vi][w+2]=v4.z; tl[vi][w+3]=v4.w;
        }
        __syncthreads();
        #pragma unroll
        for (int k = 0; k < 4; ++k) {
            const int cid = k*256 + threadIdx.x;     // 0..1023 16B-chunks
            const int vbh  = cid >> 9;
            const int wsec = (cid >> 7) & 3;
            const int w    = (cid >> 2) & 31;
            const int q    = cid & 3;
            const int vb   = h*2 + vbh;
            const int c    = vb*32 + uin;
            const int qs   = q ^ ((w >> 1) & 3);
            bf16x8 t8;
            #pragma unroll
            for (int j = 0; j < 8; ++j)
                t8[j] = (bf16)(tl[vbh*32 + q*8 + j][wsec*32 + w] * scale);
            *(bf16x8*)(wt + (size_t)(usec*4 + wsec)*SLICE_EL + (size_t)c*CHUNK_EL
                          + p*1024 + w*32 + qs*8) = t8;
        }
        __syncthreads();
    }
}

// ---- prologue: pack x1 -> [tile32][usec][u32][n128][q4]; x2 -> [n][q][v] bf16 ----
__global__ __launch_bounds__(256) void pack_x_kernel(
    const float* __restrict__ x1s, const float* __restrict__ x1v,
    const float* __restrict__ x2s, const float* __restrict__ x2v,
    bf16* __restrict__ x1g, bf16* __restrict__ x2g)
{
    if (blockIdx.x < 128) {
        __shared__ uint2 tl[128][33];
        const int nb = blockIdx.x;      // 32-node block
        #pragma unroll
        for (int k = 0; k < 16; ++k) {
            const int idx = k*256 + threadIdx.x;    // u fast
            const int u = idx & 127, nd = idx >> 7;
            const size_t i = (size_t)(nb*32 + nd)*128 + u;
            union { bf16 h[4]; uint2 u2; } tp;
            tp.h[0] = (bf16)x1s[i];
            tp.h[1] = (bf16)x1v[i*3 + 0];
            tp.h[2] = (bf16)x1v[i*3 + 1];
            tp.h[3] = (bf16)x1v[i*3 + 2];
            tl[u][nd] = tp.u2;
        }
        __syncthreads();
        uint2* og = (uint2*)x1g;
        const int t = nb >> 2, nd0 = (nb & 3) * 32;   // tile of 128 nodes
        #pragma unroll
        for (int k = 0; k < 16; ++k) {
            const int idx = k*256 + threadIdx.x;    // nd fast
            const int u = idx >> 5, nd = idx & 31;
            og[(((t*4 + (u>>5))*32 + (u&31)) << 7) + nd0 + nd] = tl[u][nd];
        }
    } else {
        const int tt = (blockIdx.x - 128)*256 + threadIdx.x;
        const int n = tt >> 7, v = tt & 127;
        const size_t b = (size_t)n*512;
        const size_t i = (size_t)n*128 + v;
        x2g[b +   0 + v] = (bf16)x2s[i];
        x2g[b + 128 + v] = (bf16)x2v[i*3 + 0];
        x2g[b + 256 + v] = (bf16)x2v[i*3 + 1];
        x2g[b + 384 + v] = (bf16)x2v[i*3 + 2];
    }
}

// ---- main: 512 WGs = 32 node-tiles(128) x 4 u-sec x 4 w-sec, 512 thr ----
// XCD-pinned slices: b&7 = XCD hosts slices {2x,2x+1} (2.5MB, L2-resident).
// wave = 16 nodes x 32 w. 2 WG/CU. Weight pipeline: 4 bufs, stage c+2 at
// body c, counted vmcnt(4) + raw s_barrier (no drain in main loop).
__global__ __launch_bounds__(512, 4) void tp_main(
    const bf16* __restrict__ wt, const bf16* __restrict__ x1g,
    const bf16* __restrict__ x2g, float* __restrict__ out)
{
    __shared__ __align__(16) bf16 wlds[4*CHUNK_EL];  // 40 KB quad-buffer weights
    __shared__ __align__(16) bf16 x1lds[16384];      // 32 KB x1 slice [u32][n128][q4]

    const int tid  = threadIdx.x;
    const int lane = tid & 63;
    const int wv   = tid >> 6;
    const int kg   = lane >> 4;
    const int lr   = lane & 15;

    const int b    = blockIdx.x;
    const int s    = (b & 7)*2 + ((b >> 3) & 1);  // weight slice 0..15 (XCD-pinned)
    const int t    = b >> 4;                      // node tile 0..31
    const int usec = s >> 2;
    const int wsec = s & 3;

    const bf16* wstream = wt + (size_t)s * SLICE_EL;

    int boff[2];
    #pragma unroll
    for (int ct = 0; ct < 2; ++ct) {
        const int wp = ct*16 + lr;
        boff[ct] = wp*32 + ((kg ^ ((wp >> 1) & 3)) * 8);
    }

    // prologue: stage x1 slice (32KB) + weight chunks 0,1; full drain once
    {
        const bf16* src = x1g + ((size_t)(t*4 + usec) << 14);
        #pragma unroll
        for (int r = 0; r < 4; ++r)
            gl_lds16(src + (wv*4 + r)*512 + lane*8, x1lds + (wv*4 + r)*512);
    }
    if (wv < 5) {
        #pragma unroll
        for (int k = 0; k < 2; ++k) {
            const bf16* sc = wstream + k*CHUNK_EL + wv*1024 + lane*8;
            bf16* dc = wlds + k*CHUNK_EL + wv*1024;
            gl_lds16(sc, dc);
            gl_lds16(sc + 512, dc + 512);
        }
    }
    __syncthreads();   // full drain (prologue only)

    f32x4 acc[2][4];
    #pragma unroll
    for (int c2 = 0; c2 < 2; ++c2)
        #pragma unroll
        for (int d = 0; d < 4; ++d)
            acc[c2][d] = (f32x4){0.f, 0.f, 0.f, 0.f};

    f32x2 xp[4][4];   // [q][vpair]
    // per-lane staging source pointer (chunk 2 onward), advanced by CHUNK_EL
    const bf16* wsrc = wstream + 2*CHUNK_EL + wv*1024 + lane*8;

    for (int vb = 0; vb < 4; ++vb) {
        // refresh x2 register slice for this v-block
        {
            const int n = t*128 + wv*16 + lr;
            #pragma unroll
            for (int q = 0; q < 4; ++q) {
                const uint4 h = *(const uint4*)(x2g + ((size_t)(n*4 + q) << 7) + vb*32 + kg*8);
                xp[q][0] = (f32x2){blo(h.x), bhi(h.x)};
                xp[q][1] = (f32x2){blo(h.y), bhi(h.y)};
                xp[q][2] = (f32x2){blo(h.z), bhi(h.z)};
                xp[q][3] = (f32x2){blo(h.w), bhi(h.w)};
            }
        }
        for (int u2 = 0; u2 < 32; ++u2) {
            const int c = vb*32 + u2;

            // stage chunk c+2 into buf[(c+2)&3] (waves 0-4, 2 loads each)
            if (c + 2 < 128 && wv < 5) {
                bf16* dc = wlds + ((c + 2) & 3)*CHUNK_EL + wv*1024;
                gl_lds16(wsrc, dc);
                gl_lds16(wsrc + 512, dc + 512);
            }
            wsrc += CHUNK_EL;

            // counted wait: chunk c's loads have >=4 younger loads in flight
            if (c < 126)       { asm volatile("s_waitcnt vmcnt(4)" ::: "memory"); }
            else if (c == 126) { asm volatile("s_waitcnt vmcnt(2)" ::: "memory"); }
            else               { asm volatile("s_waitcnt vmcnt(0)" ::: "memory"); }
            __builtin_amdgcn_s_barrier();
            __builtin_amdgcn_sched_barrier(0);

            // B fragments (5 paths x 2 col-tiles) from buf[c&3]
            bf16x8 bfr[5][2];
            const bf16* wb = wlds + (c & 3)*CHUNK_EL;
            #pragma unroll
            for (int p = 0; p < 5; ++p)
                #pragma unroll
                for (int ct = 0; ct < 2; ++ct)
                    bfr[p][ct] = *(const bf16x8*)(wb + p*1024 + boff[ct]);

            {
                const int nodel = wv*16 + lr;
                const uint2 h1 = *(const uint2*)(x1lds + u2*512 + nodel*4);
                const f32x2 ps1 = sp(blo(h1.x));
                f32x2 pv[3];
                pv[0] = sp(bhi(h1.x)); pv[1] = sp(blo(h1.y)); pv[2] = sp(bhi(h1.y));

                // ---- scalar-output channels: sss, vvs ----
                {
                    u32 f0[4], f1[4];
                    #pragma unroll
                    for (int j = 0; j < 4; ++j) {
                        const f32x2 s2 = xp[0][j];
                        f32x2 cs = pk_mul(ps1, s2);
                        f32x2 cd = pk_mul(pv[0], xp[1][j]);
                        cd = pk_fma(pv[1], xp[2][j], cd);
                        cd = pk_fma(pv[2], xp[3][j], cd);
                        f0[j] = cvtpk(cs.x, cs.y);
                        f1[j] = cvtpk(cd.x, cd.y);
                    }
                    #pragma unroll
                    for (int ct = 0; ct < 2; ++ct) {
                        acc[ct][0] = __builtin_amdgcn_mfma_f32_16x16x32_bf16(FR(f0), bfr[0][ct], acc[ct][0], 0,0,0);
                        acc[ct][0] = __builtin_amdgcn_mfma_f32_16x16x32_bf16(FR(f1), bfr[1][ct], acc[ct][0], 0,0,0);
                    }
                }
                // ---- vector-output channels per k: svv, vsv, vvv(cross) ----
                #pragma unroll
                for (int k = 0; k < 3; ++k) {
                    const int k1 = (k+1) % 3, k2 = (k+2) % 3;
                    u32 fa[4], fb[4], fc[4];
                    #pragma unroll
                    for (int j = 0; j < 4; ++j) {
                        const f32x2 s2  = xp[0][j];
                        const f32x2 vk  = xp[1+k][j];
                        const f32x2 vk1 = xp[1+k1][j];
                        const f32x2 vk2 = xp[1+k2][j];
                        f32x2 c_sv = pk_mul(ps1, vk);
                        f32x2 c_vs = pk_mul(pv[k], s2);
                        f32x2 tx   = pk_mul(pv[k1], vk2);
                        f32x2 c_x  = pk_fma_n(pv[k2], vk1, tx);
                        fa[j] = cvtpk(c_sv.x, c_sv.y);
                        fb[j] = cvtpk(c_vs.x, c_vs.y);
                        fc[j] = cvtpk(c_x.x,  c_x.y);
                    }
                    #pragma unroll
                    for (int ct = 0; ct < 2; ++ct) {
                        acc[ct][1+k] = __builtin_amdgcn_mfma_f32_16x16x32_bf16(FR(fa), bfr[2][ct], acc[ct][1+k], 0,0,0);
                        acc[ct][1+k] = __builtin_amdgcn_mfma_f32_16x16x32_bf16(FR(fb), bfr[3][ct], acc[ct][1+k], 0,0,0);
                        acc[ct][1+k] = __builtin_amdgcn_mfma_f32_16x16x32_bf16(FR(fc), bfr[4][ct], acc[ct][1+k], 0,0,0);
                    }
                }
            }
        }
    }

    // epilogue: accumulate u-section partials into d_out
    #pragma unroll
    for (int ct = 0; ct < 2; ++ct) {
        const int w = wsec*32 + ct*16 + lr;
        #pragma unroll
        for (int j = 0; j < 4; ++j) {
            const int n = t*128 + wv*16 + kg*4 + j;
            float* op = out + (size_t)n*512;
            unsafeAtomicAdd(op + w,             acc[ct][0][j]);
            unsafeAtomicAdd(op + 128 + w*3 + 0, acc[ct][1][j]);
            unsafeAtomicAdd(op + 128 + w*3 + 1, acc[ct][2][j]);
            unsafeAtomicAdd(op + 128 + w*3 + 2, acc[ct][3][j]);
        }
    }
}

extern "C" void kernel_launch(void* const* d_in, const int* in_sizes, int n_in,
                              void* d_out, int out_size, void* d_ws, size_t ws_size,
                              hipStream_t stream)
{
    const float* x1s = (const float*)d_in[0];
    const float* x1v = (const float*)d_in[1];
    const float* x2s = (const float*)d_in[2];
    const float* x2v = (const float*)d_in[3];
    const float* w0  = (const float*)d_in[4];
    const float* w1  = (const float*)d_in[5];
    const float* w2  = (const float*)d_in[6];
    const float* w3  = (const float*)d_in[7];
    const float* w4  = (const float*)d_in[8];

    bf16* wtb = (bf16*)d_ws;
    bf16* x1g = (bf16*)((char*)d_ws + WT_BYTES);
    bf16* x2g = (bf16*)((char*)d_ws + WT_BYTES + X1_BYTES);
    float* out = (float*)d_out;

    pack_w_kernel<<<640, 256, 0, stream>>>(w0, w1, w2, w3, w4, wtb);
    pack_x_kernel<<<2176, 256, 0, stream>>>(x1s, x1v, x2s, x2v, x1g, x2g);
    hipMemsetAsync(d_out, 0, (size_t)out_size*sizeof(float), stream);
    tp_main<<<512, 512, 0, stream>>>(wtb, x1g, x2g, out);
}

// Round 7
// 239.506 us; speedup vs baseline: 1.4311x; 1.3077x over previous
//
#include <hip/hip_runtime.h>
#include <hip/hip_bf16.h>

// e3nn FullyConnectedTensorProduct (128x0e+128x1o)^2 -> 128x0e+128x1o, N=4096
// R7: fp16 MFMA + v_pk_*_f16 A-gen (packed result IS the frag word: no cvt,
//     no assembly moves), xq 32->16 VGPRs (kills the R5/R6 spill), unrolled
//     x4 inner loop for static LDS buffer offsets. Counted-vmcnt pipeline kept.
// ws layout: [WT f16 20MB][X1g f16 4MB][X2g f16 4MB]

typedef _Float16 f16;
typedef _Float16 f16x8 __attribute__((ext_vector_type(8)));
typedef float f32x4 __attribute__((ext_vector_type(4)));
typedef unsigned u32;

#define WT_BYTES  (5u*4u*128u*4096u*2u)     // 20971520 B = 16 slices x 655360 el x 2B
#define X1_BYTES  (32u*4u*16384u*2u)        // 4194304  ([tile32][usec4][u32][n128][q4] f16)
#define SLICE_EL  655360u                    // elems per slice = 128 chunks x 5120
#define CHUNK_EL  5120u                      // elems per K-chunk (10 KB)

__device__ __forceinline__ u32 pkmul16(u32 a, u32 b){
    u32 r; asm("v_pk_mul_f16 %0, %1, %2" : "=v"(r) : "v"(a), "v"(b)); return r;
}
__device__ __forceinline__ u32 pkfma16(u32 a, u32 b, u32 c){
    u32 r; asm("v_pk_fma_f16 %0, %1, %2, %3" : "=v"(r) : "v"(a), "v"(b), "v"(c)); return r;
}
__device__ __forceinline__ u32 pkfma16n(u32 a, u32 b, u32 c){  // -a*b + c
    u32 r; asm("v_pk_fma_f16 %0, %1, %2, %3 neg_lo:[1,0,0] neg_hi:[1,0,0]"
               : "=v"(r) : "v"(a), "v"(b), "v"(c)); return r;
}

union Frag { u32 u[4]; f16x8 v; };
__device__ __forceinline__ f16x8 FR(const u32 a[4]){
    Frag f; f.u[0]=a[0]; f.u[1]=a[1]; f.u[2]=a[2]; f.u[3]=a[3]; return f.v;
}

__device__ __forceinline__ void gl_lds16(const f16* g, f16* l) {
    __builtin_amdgcn_global_load_lds(
        (const __attribute__((address_space(1))) void*)g,
        (__attribute__((address_space(3))) void*)l,
        16, 0, 0);
}

// ---- prologue: weights f32 [u][v][w] -> WT[slice][c][p][32w][4q-swz][8v] f16 ----
__global__ __launch_bounds__(256) void pack_w_kernel(
    const float* __restrict__ w0, const float* __restrict__ w1,
    const float* __restrict__ w2, const float* __restrict__ w3,
    const float* __restrict__ w4, f16* __restrict__ wt)
{
    __shared__ float tl[64][130];
    const int b = blockIdx.x;           // 640 = 5 paths x 128 u
    const int p = b >> 7;
    const int u = b & 127;
    const int usec = u >> 5;
    const int uin  = u & 31;
    const float* src = (p==0)?w0:(p==1)?w1:(p==2)?w2:(p==3)?w3:w4;
    const float scale = (p==0)?1.0f:(p==4)?0.40824829046386302f:0.57735026918962576f;

    for (int h = 0; h < 2; ++h) {       // two 64-v halves
        const float* spR = src + (size_t)u*16384 + (size_t)h*8192;
        #pragma unroll
        for (int k = 0; k < 8; ++k) {
            const int e4 = (k*256 + threadIdx.x) * 4;
            const float4 v4 = *(const float4*)(spR + e4);
            const int vi = e4 >> 7, w = e4 & 127;
            tl[vi][w+0]=v4.x; tl[vi][w+1]=v4.y; tl[vi][w+2]=v4.z; tl[vi][w+3]=v4.w;
        }
        __syncthreads();
        #pragma unroll
        for (int k = 0; k < 4; ++k) {
            const int cid = k*256 + threadIdx.x;     // 0..1023 16B-chunks
            const int vbh  = cid >> 9;
            const int wsec = (cid >> 7) & 3;
            const int w    = (cid >> 2) & 31;
            const int q    = cid & 3;
            const int vb   = h*2 + vbh;
            const int c    = vb*32 + uin;
            const int qs   = q ^ ((w >> 1) & 3);
            f16x8 t8;
            #pragma unroll
            for (int j = 0; j < 8; ++j)
                t8[j] = (f16)(tl[vbh*32 + q*8 + j][wsec*32 + w] * scale);
            *(f16x8*)(wt + (size_t)(usec*4 + wsec)*SLICE_EL + (size_t)c*CHUNK_EL
                          + p*1024 + w*32 + qs*8) = t8;
        }
        __syncthreads();
    }
}

// ---- prologue: pack x1 -> [tile32][usec][u32][n128][q4]; x2 -> [n][q][v] f16 ----
__global__ __launch_bounds__(256) void pack_x_kernel(
    const float* __restrict__ x1s, const float* __restrict__ x1v,
    const float* __restrict__ x2s, const float* __restrict__ x2v,
    f16* __restrict__ x1g, f16* __restrict__ x2g)
{
    if (blockIdx.x < 128) {
        __shared__ uint2 tl[128][33];
        const int nb = blockIdx.x;      // 32-node block
        #pragma unroll
        for (int k = 0; k < 16; ++k) {
            const int idx = k*256 + threadIdx.x;    // u fast
            const int u = idx & 127, nd = idx >> 7;
            const size_t i = (size_t)(nb*32 + nd)*128 + u;
            union { f16 h[4]; uint2 u2; } tp;
            tp.h[0] = (f16)x1s[i];
            tp.h[1] = (f16)x1v[i*3 + 0];
            tp.h[2] = (f16)x1v[i*3 + 1];
            tp.h[3] = (f16)x1v[i*3 + 2];
            tl[u][nd] = tp.u2;
        }
        __syncthreads();
        uint2* og = (uint2*)x1g;
        const int t = nb >> 2, nd0 = (nb & 3) * 32;   // tile of 128 nodes
        #pragma unroll
        for (int k = 0; k < 16; ++k) {
            const int idx = k*256 + threadIdx.x;    // nd fast
            const int u = idx >> 5, nd = idx & 31;
            og[(((t*4 + (u>>5))*32 + (u&31)) << 7) + nd0 + nd] = tl[u][nd];
        }
    } else {
        const int tt = (blockIdx.x - 128)*256 + threadIdx.x;
        const int n = tt >> 7, v = tt & 127;
        const size_t b = (size_t)n*512;
        const size_t i = (size_t)n*128 + v;
        x2g[b +   0 + v] = (f16)x2s[i];
        x2g[b + 128 + v] = (f16)x2v[i*3 + 0];
        x2g[b + 256 + v] = (f16)x2v[i*3 + 1];
        x2g[b + 384 + v] = (f16)x2v[i*3 + 2];
    }
}

// ---- main: 512 WGs = 32 node-tiles(128) x 4 u-sec x 4 w-sec, 512 thr ----
// XCD-pinned slices: b&7 = XCD hosts slices {2x,2x+1} (2.5MB, L2-resident).
// wave = 16 nodes x 32 w. 2 WG/CU. 4-buf weight pipeline, stage c+2 at body c,
// counted vmcnt(4) + raw s_barrier. fp16 packed A-gen.
__global__ __launch_bounds__(512, 4) void tp_main(
    const f16* __restrict__ wt, const f16* __restrict__ x1g,
    const f16* __restrict__ x2g, float* __restrict__ out)
{
    __shared__ __align__(16) f16 wlds[4*CHUNK_EL];  // 40 KB quad-buffer weights
    __shared__ __align__(16) f16 x1lds[16384];      // 32 KB x1 slice [u32][n128][q4]

    const int tid  = threadIdx.x;
    const int lane = tid & 63;
    const int wv   = tid >> 6;
    const int kg   = lane >> 4;
    const int lr   = lane & 15;

    const int b    = blockIdx.x;
    const int s    = (b & 7)*2 + ((b >> 3) & 1);  // weight slice 0..15 (XCD-pinned)
    const int t    = b >> 4;                      // node tile 0..31
    const int usec = s >> 2;
    const int wsec = s & 3;

    const f16* wstream = wt + (size_t)s * SLICE_EL;

    int boff[2];
    #pragma unroll
    for (int ct = 0; ct < 2; ++ct) {
        const int wp = ct*16 + lr;
        boff[ct] = wp*32 + ((kg ^ ((wp >> 1) & 3)) * 8);
    }

    // prologue: stage x1 slice (32KB) + weight chunks 0,1; full drain once
    {
        const f16* src = x1g + ((size_t)(t*4 + usec) << 14);
        #pragma unroll
        for (int r = 0; r < 4; ++r)
            gl_lds16(src + (wv*4 + r)*512 + lane*8, x1lds + (wv*4 + r)*512);
    }
    if (wv < 5) {
        #pragma unroll
        for (int k = 0; k < 2; ++k) {
            const f16* sc = wstream + k*CHUNK_EL + wv*1024 + lane*8;
            f16* dc = wlds + k*CHUNK_EL + wv*1024;
            gl_lds16(sc, dc);
            gl_lds16(sc + 512, dc + 512);
        }
    }
    __syncthreads();   // full drain (prologue only)

    f32x4 acc[2][4];
    #pragma unroll
    for (int c2 = 0; c2 < 2; ++c2)
        #pragma unroll
        for (int d = 0; d < 4; ++d)
            acc[c2][d] = (f32x4){0.f, 0.f, 0.f, 0.f};

    u32 xq[4][4];   // [q][k-pair]: packed f16 pairs, lane's 8 k-values per q
    const f16* wsrc = wstream + 2*CHUNK_EL + wv*1024 + lane*8;
    const f16* x2base = x2g + ((size_t)(t*128 + wv*16 + lr) << 9) + kg*8;

    for (int vb = 0; vb < 4; ++vb) {
        // refresh x2 packed registers for this v-block
        {
            const f16* xb = x2base + vb*32;
            #pragma unroll
            for (int q = 0; q < 4; ++q) {
                const uint4 h = *(const uint4*)(xb + (q << 7));
                xq[q][0] = h.x; xq[q][1] = h.y; xq[q][2] = h.z; xq[q][3] = h.w;
            }
        }
        for (int u2b = 0; u2b < 32; u2b += 4) {
            #pragma unroll
            for (int uu = 0; uu < 4; ++uu) {       // buffer index = uu (static)
                const int u2 = u2b + uu;
                const int c  = vb*32 + u2;

                // stage chunk c+2 into buf[(uu+2)&3] (waves 0-4, 2 loads each)
                if (c < 126 && wv < 5) {
                    f16* dc = wlds + ((uu + 2) & 3)*CHUNK_EL + wv*1024;
                    gl_lds16(wsrc, dc);
                    gl_lds16(wsrc + 512, dc + 512);
                }
                wsrc += CHUNK_EL;

                // counted wait: keep the 4 newest (chunks c+1,c+2) in flight
                if (c < 126)       { asm volatile("s_waitcnt vmcnt(4)" ::: "memory"); }
                else if (c == 126) { asm volatile("s_waitcnt vmcnt(2)" ::: "memory"); }
                else               { asm volatile("s_waitcnt vmcnt(0)" ::: "memory"); }
                __builtin_amdgcn_s_barrier();
                __builtin_amdgcn_sched_barrier(0);

                // B fragments (5 paths x 2 col-tiles) from buf[uu]
                f16x8 bfr[5][2];
                const f16* wb = wlds + uu*CHUNK_EL;
                #pragma unroll
                for (int p = 0; p < 5; ++p)
                    #pragma unroll
                    for (int ct = 0; ct < 2; ++ct)
                        bfr[p][ct] = *(const f16x8*)(wb + p*1024 + boff[ct]);

                // x1 broadcasts (packed f16 pairs via v_perm)
                const uint2 h1 = *(const uint2*)(x1lds + u2*512 + (wv*16 + lr)*4);
                const u32 ps1 = __builtin_amdgcn_perm(h1.x, h1.x, 0x01000100u);
                u32 pv[3];
                pv[0] = __builtin_amdgcn_perm(h1.x, h1.x, 0x03020302u);
                pv[1] = __builtin_amdgcn_perm(h1.y, h1.y, 0x01000100u);
                pv[2] = __builtin_amdgcn_perm(h1.y, h1.y, 0x03020302u);

                // ---- scalar-output channels: sss, vvs ----
                {
                    u32 f0[4], f1[4];
                    #pragma unroll
                    for (int j = 0; j < 4; ++j) {
                        f0[j] = pkmul16(ps1, xq[0][j]);
                        u32 d = pkmul16(pv[0], xq[1][j]);
                        d     = pkfma16(pv[1], xq[2][j], d);
                        f1[j] = pkfma16(pv[2], xq[3][j], d);
                    }
                    #pragma unroll
                    for (int ct = 0; ct < 2; ++ct) {
                        acc[ct][0] = __builtin_amdgcn_mfma_f32_16x16x32_f16(FR(f0), bfr[0][ct], acc[ct][0], 0,0,0);
                        acc[ct][0] = __builtin_amdgcn_mfma_f32_16x16x32_f16(FR(f1), bfr[1][ct], acc[ct][0], 0,0,0);
                    }
                }
                // ---- vector-output channels per k: svv, vsv, vvv(cross) ----
                #pragma unroll
                for (int k = 0; k < 3; ++k) {
                    const int k1 = (k+1) % 3, k2 = (k+2) % 3;
                    u32 fa[4], fb[4], fc[4];
                    #pragma unroll
                    for (int j = 0; j < 4; ++j) {
                        fa[j] = pkmul16(ps1,    xq[1+k][j]);
                        fb[j] = pkmul16(pv[k],  xq[0][j]);
                        u32 tx = pkmul16(pv[k1], xq[1+k2][j]);
                        fc[j] = pkfma16n(pv[k2], xq[1+k1][j], tx);
                    }
                    #pragma unroll
                    for (int ct = 0; ct < 2; ++ct) {
                        acc[ct][1+k] = __builtin_amdgcn_mfma_f32_16x16x32_f16(FR(fa), bfr[2][ct], acc[ct][1+k], 0,0,0);
                        acc[ct][1+k] = __builtin_amdgcn_mfma_f32_16x16x32_f16(FR(fb), bfr[3][ct], acc[ct][1+k], 0,0,0);
                        acc[ct][1+k] = __builtin_amdgcn_mfma_f32_16x16x32_f16(FR(fc), bfr[4][ct], acc[ct][1+k], 0,0,0);
                    }
                }
            }
        }
    }

    // epilogue: accumulate u-section partials into d_out
    #pragma unroll
    for (int ct = 0; ct < 2; ++ct) {
        const int w = wsec*32 + ct*16 + lr;
        #pragma unroll
        for (int j = 0; j < 4; ++j) {
            const int n = t*128 + wv*16 + kg*4 + j;
            float* op = out + (size_t)n*512;
            unsafeAtomicAdd(op + w,             acc[ct][0][j]);
            unsafeAtomicAdd(op + 128 + w*3 + 0, acc[ct][1][j]);
            unsafeAtomicAdd(op + 128 + w*3 + 1, acc[ct][2][j]);
            unsafeAtomicAdd(op + 128 + w*3 + 2, acc[ct][3][j]);
        }
    }
}

extern "C" void kernel_launch(void* const* d_in, const int* in_sizes, int n_in,
                              void* d_out, int out_size, void* d_ws, size_t ws_size,
                              hipStream_t stream)
{
    const float* x1s = (const float*)d_in[0];
    const float* x1v = (const float*)d_in[1];
    const float* x2s = (const float*)d_in[2];
    const float* x2v = (const float*)d_in[3];
    const float* w0  = (const float*)d_in[4];
    const float* w1  = (const float*)d_in[5];
    const float* w2  = (const float*)d_in[6];
    const float* w3  = (const float*)d_in[7];
    const float* w4  = (const float*)d_in[8];

    f16* wtb = (f16*)d_ws;
    f16* x1g = (f16*)((char*)d_ws + WT_BYTES);
    f16* x2g = (f16*)((char*)d_ws + WT_BYTES + X1_BYTES);
    float* out = (float*)d_out;

    pack_w_kernel<<<640, 256, 0, stream>>>(w0, w1, w2, w3, w4, wtb);
    pack_x_kernel<<<2176, 256, 0, stream>>>(x1s, x1v, x2s, x2v, x1g, x2g);
    hipMemsetAsync(d_out, 0, (size_t)out_size*sizeof(float), stream);
    tp_main<<<512, 512, 0, stream>>>(wtb, x1g, x2g, out);
}